// Round 11
// baseline (391.991 us; speedup 1.0000x reference)
//
#include <hip/hip_runtime.h>
#include <math.h>

#define F 128
#define SCAN_CHUNK 1024
#define CHUNK 32   // nodes per chunk in fused layer kernel
#define NBLK 128   // writer blocks in hist/binfill

typedef __attribute__((ext_vector_type(8))) short bf16x8;
typedef __attribute__((ext_vector_type(4))) float f32x4;

__device__ inline unsigned short f2bf(float v) {  // fp32 -> bf16 RNE
  unsigned u = __float_as_uint(v);
  unsigned r = (u + 0x7FFFu + ((u >> 16) & 1u)) >> 16;
  return (unsigned short)r;
}
__device__ inline float bf2f(unsigned short s) {
  return __uint_as_float(((unsigned)s) << 16);
}

// ---------- fused: dual bucket histogram + x -> bf16 conversion ----------
__global__ __launch_bounds__(1024) void k_prep2(const int* __restrict__ src,
                                                const int* __restrict__ dst,
                                                const float* __restrict__ x,
                                                unsigned short* __restrict__ xb,
                                                int* __restrict__ cntgD,
                                                int* __restrict__ cntgS, int E,
                                                int NF4, int nb, int per) {
  extern __shared__ int smem[];
  int* cd = smem;
  int* cs = smem + nb;
  int blk = blockIdx.x;
  int tid = threadIdx.x;
  for (int b = tid; b < nb; b += 1024) {
    cd[b] = 0;
    cs[b] = 0;
  }
  __syncthreads();
  int e0 = blk * per;
  int e1 = e0 + per;
  if (e1 > E) e1 = E;
  for (int e = e0 + tid; e < e1; e += 1024) {
    atomicAdd(&cd[dst[e] >> 7], 1);
    atomicAdd(&cs[src[e] >> 7], 1);
  }
  const float4* x4 = (const float4*)x;
  ushort4* xb4 = (ushort4*)xb;
  for (int i = blk * 1024 + tid; i < NF4; i += NBLK * 1024) {
    float4 v = x4[i];
    ushort4 o;
    o.x = f2bf(v.x);
    o.y = f2bf(v.y);
    o.z = f2bf(v.z);
    o.w = f2bf(v.w);
    xb4[i] = o;
  }
  __syncthreads();
  for (int b = tid; b < nb; b += 1024) {
    cntgD[b * NBLK + blk] = cd[b];
    cntgS[b * NBLK + blk] = cs[b];
  }
}

// per-bucket exclusive scan over NBLK writer blocks; emit bucket totals
__global__ __launch_bounds__(NBLK) void k_scanBk2(int* __restrict__ cntgD,
                                                  int* __restrict__ cntgS,
                                                  int* __restrict__ totD,
                                                  int* __restrict__ totS, int nb) {
  __shared__ int sh[NBLK];
  int b = blockIdx.x;
  int tid = threadIdx.x;
  int* cntg;
  int* tot;
  int bb;
  if (b < nb) {
    cntg = cntgD;
    tot = totD;
    bb = b;
  } else {
    cntg = cntgS;
    tot = totS;
    bb = b - nb;
  }
  int v = cntg[bb * NBLK + tid];
  int val = v;
  sh[tid] = val;
  __syncthreads();
  for (int off = 1; off < NBLK; off <<= 1) {
    int o = (tid >= off) ? sh[tid - off] : 0;
    __syncthreads();
    val += o;
    sh[tid] = val;
    __syncthreads();
  }
  cntg[bb * NBLK + tid] = val - v;  // exclusive within bucket
  if (tid == NBLK - 1) tot[bb] = val;
}

// exclusive scan of bucket totals -> bases (nb <= 1024); sentinel = E
__global__ __launch_bounds__(1024) void k_scanTot(const int* __restrict__ totD,
                                                  const int* __restrict__ totS,
                                                  int* __restrict__ baseD,
                                                  int* __restrict__ baseS, int nb,
                                                  int E) {
  __shared__ int sh[1024];
  int tid = threadIdx.x;
  int v = (tid < nb) ? totD[tid] : 0;
  int val = v;
  sh[tid] = val;
  __syncthreads();
  for (int off = 1; off < 1024; off <<= 1) {
    int o = (tid >= off) ? sh[tid - off] : 0;
    __syncthreads();
    val += o;
    sh[tid] = val;
    __syncthreads();
  }
  if (tid < nb) baseD[tid] = val - v;
  if (tid == 0) baseD[nb] = E;
  __syncthreads();
  v = (tid < nb) ? totS[tid] : 0;
  val = v;
  sh[tid] = val;
  __syncthreads();
  for (int off = 1; off < 1024; off <<= 1) {
    int o = (tid >= off) ? sh[tid - off] : 0;
    __syncthreads();
    val += o;
    sh[tid] = val;
    __syncthreads();
  }
  if (tid < nb) baseS[tid] = val - v;
  if (tid == 0) baseS[nb] = E;
}

// scatter edges into bucket-grouped arrays (no global atomics)
__global__ __launch_bounds__(1024) void k_binfill2(
    const int* __restrict__ src, const int* __restrict__ dst,
    const int* __restrict__ cntgD, const int* __restrict__ cntgS,
    const int* __restrict__ baseD, const int* __restrict__ baseS,
    unsigned* __restrict__ binnedD, unsigned char* __restrict__ binnedS, int E,
    int nb, int per) {
  extern __shared__ int smem[];
  int* bD = smem;
  int* cD = smem + nb;
  int* bS = smem + 2 * nb;
  int* cS = smem + 3 * nb;
  int blk = blockIdx.x;
  for (int b = threadIdx.x; b < nb; b += 1024) {
    bD[b] = baseD[b] + cntgD[b * NBLK + blk];
    cD[b] = 0;
    bS[b] = baseS[b] + cntgS[b * NBLK + blk];
    cS[b] = 0;
  }
  __syncthreads();
  int e0 = blk * per;
  int e1 = e0 + per;
  if (e1 > E) e1 = E;
  for (int e = e0 + threadIdx.x; e < e1; e += 1024) {
    int s = src[e];
    int d = dst[e];
    int bk = d >> 7;
    int rk = atomicAdd(&cD[bk], 1);
    binnedD[bD[bk] + rk] = ((unsigned)s << 7) | (unsigned)(d & 127);
    int bs = s >> 7;
    int rs = atomicAdd(&cS[bs], 1);
    binnedS[bS[bs] + rs] = (unsigned char)(s & 127);
  }
}

// fused per-bucket: dinv (from src byte stream) + rp/pairs (from dst stream)
__global__ __launch_bounds__(256) void k_csr(const unsigned char* __restrict__ binnedS,
                                             const int* __restrict__ baseS,
                                             const unsigned* __restrict__ binnedD,
                                             const int* __restrict__ baseD,
                                             float* __restrict__ dinv,
                                             int* __restrict__ rp,
                                             int* __restrict__ pairs, int N, int E) {
  __shared__ int cnt[128];
  __shared__ int sc[256];
  __shared__ int cur[128];
  int b = blockIdx.x;
  int tid = threadIdx.x;
  int node0 = b << 7;
  if (tid < 128) cnt[tid] = 0;
  __syncthreads();
  int sbeg = baseS[b], send = baseS[b + 1];
  for (int j = sbeg + tid; j < send; j += 256) atomicAdd(&cnt[binnedS[j]], 1);
  __syncthreads();
  if (tid < 128) {
    int node = node0 + tid;
    if (node < N) {
      int c = cnt[tid];
      dinv[node] = c > 0 ? rsqrtf((float)c) : 0.0f;
    }
    cnt[tid] = 0;
  }
  __syncthreads();
  int wbeg = baseD[b], wend = baseD[b + 1];
  for (int j = wbeg + tid; j < wend; j += 256) atomicAdd(&cnt[binnedD[j] & 127u], 1);
  __syncthreads();
  int v = (tid < 128) ? cnt[tid] : 0;
  int val = v;
  sc[tid] = val;
  __syncthreads();
  for (int off = 1; off < 128; off <<= 1) {
    int o = (tid >= off) ? sc[tid - off] : 0;
    __syncthreads();
    val += o;
    sc[tid] = val;
    __syncthreads();
  }
  if (tid < 128) {
    int excl = wbeg + val - v;
    int node = node0 + tid;
    if (node < N) rp[node] = excl;
    cur[tid] = excl;
  }
  if (b == 0 && tid == 0) rp[N] = E;
  __syncthreads();
  for (int j = wbeg + tid; j < wend; j += 256) {
    unsigned e = binnedD[j];
    int idx = atomicAdd(&cur[e & 127u], 1);
    pairs[idx] = (int)(e >> 7);
  }
}

// ---------- fallback path (atomic degrees + scan), for huge N ----------
__global__ __launch_bounds__(256) void k_prep(const int* __restrict__ src,
                                              const int* __restrict__ dst,
                                              const float* __restrict__ x,
                                              int* __restrict__ degA,
                                              int* __restrict__ degB,
                                              unsigned short* __restrict__ xb,
                                              int E, int NF4) {
  int t0 = blockIdx.x * 256 + threadIdx.x;
  int stride = gridDim.x * 256;
  for (int i = t0; i < E; i += stride) {
    atomicAdd(&degA[src[i]], 1);
    atomicAdd(&degB[dst[i]], 1);
  }
  const float4* x4 = (const float4*)x;
  ushort4* xb4 = (ushort4*)xb;
  for (int i = t0; i < NF4; i += stride) {
    float4 v = x4[i];
    ushort4 o;
    o.x = f2bf(v.x);
    o.y = f2bf(v.y);
    o.z = f2bf(v.z);
    o.w = f2bf(v.w);
    xb4[i] = o;
  }
}

__global__ __launch_bounds__(256) void k_scanA(const int* __restrict__ deg,
                                               int* __restrict__ rp,
                                               int* __restrict__ bsum, int N) {
  __shared__ int sh[256];
  int tid = threadIdx.x;
  int base = blockIdx.x * SCAN_CHUNK + tid * 4;
  int v0 = 0, v1 = 0, v2 = 0, v3 = 0;
  if (base + 0 < N) v0 = deg[base + 0];
  if (base + 1 < N) v1 = deg[base + 1];
  if (base + 2 < N) v2 = deg[base + 2];
  if (base + 3 < N) v3 = deg[base + 3];
  int ts = v0 + v1 + v2 + v3;
  int val = ts;
  sh[tid] = val;
  __syncthreads();
  for (int off = 1; off < 256; off <<= 1) {
    int other = (tid >= off) ? sh[tid - off] : 0;
    __syncthreads();
    val += other;
    sh[tid] = val;
    __syncthreads();
  }
  int excl = val - ts;
  if (base + 0 < N) rp[base + 0] = excl;
  if (base + 1 < N) rp[base + 1] = excl + v0;
  if (base + 2 < N) rp[base + 2] = excl + v0 + v1;
  if (base + 3 < N) rp[base + 3] = excl + v0 + v1 + v2;
  if (tid == 255) bsum[blockIdx.x] = val;
}

__global__ __launch_bounds__(256) void k_scanB(int* __restrict__ bsum, int nb) {
  __shared__ int sh[256];
  int tid = threadIdx.x;
  int ts = (tid < nb) ? bsum[tid] : 0;
  int val = ts;
  sh[tid] = val;
  __syncthreads();
  for (int off = 1; off < 256; off <<= 1) {
    int other = (tid >= off) ? sh[tid - off] : 0;
    __syncthreads();
    val += other;
    sh[tid] = val;
    __syncthreads();
  }
  if (tid < nb) bsum[tid] = val - ts;
}

__global__ __launch_bounds__(256) void k_scanC(int* __restrict__ rp,
                                               const int* __restrict__ bsum,
                                               int* __restrict__ pos,
                                               const int* __restrict__ degA,
                                               float* __restrict__ dinv, int N,
                                               int E) {
  int i = blockIdx.x * 256 + threadIdx.x;
  if (i < N) {
    int v = rp[i] + bsum[i >> 10];
    rp[i] = v;
    pos[i] = v;
    int d = degA[i];
    dinv[i] = d > 0 ? rsqrtf((float)d) : 0.0f;
  }
  if (i == 0) rp[N] = E;
}

__global__ __launch_bounds__(256) void k_fill(const int* __restrict__ src,
                                              const int* __restrict__ dst,
                                              int* __restrict__ pos,
                                              int* __restrict__ pairs, int E) {
  for (int e = blockIdx.x * 256 + threadIdx.x; e < E; e += gridDim.x * 256) {
    int s = src[e];
    int d = dst[e];
    int idx = atomicAdd(&pos[d], 1);
    pairs[idx] = s;
  }
}

// ---------- fused gather + MFMA layer ----------
// Per 32-node chunk: t-rows gathered straight into LDS A-tile (no tb buffer),
// H = relu(Xb@W10h + T@W11h + b1); p = H.w20; r = dinv*(H.w21).
__global__ __launch_bounds__(256) void k_fused(
    const int* __restrict__ pairs, const int* __restrict__ rp,
    const unsigned short* __restrict__ xb, const float* __restrict__ dinv,
    const float* __restrict__ w10, const float* __restrict__ w11,
    const float* __restrict__ b1, const float* __restrict__ w20,
    const float* __restrict__ w21, float* __restrict__ p, float* __restrict__ r,
    int N) {
  __shared__ __align__(16) short Ax[8 * 16 * 40];
  __shared__ __align__(16) short At[8 * 16 * 40];
  __shared__ float p_sh[CHUNK], r_sh[CHUNK];

  const int tid = threadIdx.x;
  const int wave = tid >> 6;
  const int lane = tid & 63;
  const int quad = lane >> 4;
  const int col = lane & 15;

  // B fragments (hi only): weights are bf16-rounded; lo-term ~1e-3 in h, negligible
  bf16x8 B0[4][2], B1[4][2];
  float b1f[2], w20f[2], w21f[2];
#pragma unroll
  for (int nt = 0; nt < 2; ++nt) {
    int f = wave * 32 + nt * 16 + col;
    b1f[nt] = b1[f];
    w20f[nt] = w20[f];
    w21f[nt] = w21[f];
  }
#pragma unroll
  for (int ks = 0; ks < 4; ++ks) {
#pragma unroll
    for (int nt = 0; nt < 2; ++nt) {
      int f = wave * 32 + nt * 16 + col;
      bf16x8 h0, h1;
#pragma unroll
      for (int j = 0; j < 8; ++j) {
        h0[j] = (short)f2bf(w10[(ks * 32 + quad * 8 + j) * F + f]);
        h1[j] = (short)f2bf(w11[(ks * 32 + quad * 8 + j) * F + f]);
      }
      B0[ks][nt] = h0;
      B1[ks][nt] = h1;
    }
  }

  int node0 = blockIdx.x * CHUNK;

  // ---- stage Xb rows (sequential, coalesced) ----
  {
    int nloc = tid >> 3;
    int k0 = (tid & 7) * 16;
    int gn = node0 + nloc;
    int mt = nloc >> 4, m = nloc & 15, ks = k0 >> 5, koff = k0 & 31;
    int base = ((mt * 4 + ks) * 16 + m) * 40 + koff;
    const uint2* xr = (const uint2*)(xb + (size_t)gn * F + k0);
    bool ok = (gn < N);
#pragma unroll
    for (int q4 = 0; q4 < 4; ++q4) {
      uint2 xv = ok ? xr[q4] : make_uint2(0u, 0u);
      *(uint2*)&Ax[base + q4 * 4] = xv;
    }
    if (tid < CHUNK) {
      p_sh[tid] = 0.f;
      r_sh[tid] = 0.f;
    }
  }

  // ---- gather T rows into LDS (half-wave per node, 4 nodes each) ----
  {
    int hw = tid >> 5;       // 0..7
    int li = tid & 31;       // lane covers features li*4 .. li*4+3
    const uint2* x2 = (const uint2*)xb;
    int ks = li >> 3, koff = (li & 7) * 4;
#pragma unroll 1
    for (int nn = 0; nn < 4; ++nn) {
      int nloc = hw * 4 + nn;
      int gn = node0 + nloc;
      float a0 = 0.f, a1 = 0.f, a2 = 0.f, a3 = 0.f;
      float nd = 0.f;
      if (gn < N) {
        int beg = rp[gn], end = rp[gn + 1];
        int j = beg;
        for (; j + 3 < end; j += 4) {  // 4 row-loads in flight
          int s0 = pairs[j], s1 = pairs[j + 1], s2 = pairs[j + 2], s3 = pairs[j + 3];
          float w0 = dinv[s0], w1 = dinv[s1], w2 = dinv[s2], w3 = dinv[s3];
          uint2 v0 = x2[(size_t)s0 * 32 + li];
          uint2 v1 = x2[(size_t)s1 * 32 + li];
          uint2 v2 = x2[(size_t)s2 * 32 + li];
          uint2 v3 = x2[(size_t)s3 * 32 + li];
          a0 += w0 * bf2f((unsigned short)v0.x) + w1 * bf2f((unsigned short)v1.x) +
                w2 * bf2f((unsigned short)v2.x) + w3 * bf2f((unsigned short)v3.x);
          a1 += w0 * bf2f((unsigned short)(v0.x >> 16)) +
                w1 * bf2f((unsigned short)(v1.x >> 16)) +
                w2 * bf2f((unsigned short)(v2.x >> 16)) +
                w3 * bf2f((unsigned short)(v3.x >> 16));
          a2 += w0 * bf2f((unsigned short)v0.y) + w1 * bf2f((unsigned short)v1.y) +
                w2 * bf2f((unsigned short)v2.y) + w3 * bf2f((unsigned short)v3.y);
          a3 += w0 * bf2f((unsigned short)(v0.y >> 16)) +
                w1 * bf2f((unsigned short)(v1.y >> 16)) +
                w2 * bf2f((unsigned short)(v2.y >> 16)) +
                w3 * bf2f((unsigned short)(v3.y >> 16));
        }
        for (; j < end; ++j) {
          int s0 = pairs[j];
          float w0 = dinv[s0];
          uint2 v0 = x2[(size_t)s0 * 32 + li];
          a0 += w0 * bf2f((unsigned short)v0.x);
          a1 += w0 * bf2f((unsigned short)(v0.x >> 16));
          a2 += w0 * bf2f((unsigned short)v0.y);
          a3 += w0 * bf2f((unsigned short)(v0.y >> 16));
        }
        nd = -dinv[gn];
      }
      int mt = nloc >> 4, m = nloc & 15;
      int base = ((mt * 4 + ks) * 16 + m) * 40 + koff;
      short4 o;
      o.x = (short)f2bf(nd * a0);
      o.y = (short)f2bf(nd * a1);
      o.z = (short)f2bf(nd * a2);
      o.w = (short)f2bf(nd * a3);
      *(short4*)&At[base] = o;
    }
  }
  __syncthreads();

  // ---- MFMA: 2 terms per fragment ----
  f32x4 acc[2][2];
#pragma unroll
  for (int mt = 0; mt < 2; ++mt)
#pragma unroll
    for (int nt = 0; nt < 2; ++nt) acc[mt][nt] = (f32x4)0.f;

#pragma unroll
  for (int mt = 0; mt < 2; ++mt) {
#pragma unroll
    for (int ks = 0; ks < 4; ++ks) {
      int ab = ((mt * 4 + ks) * 16 + col) * 40 + quad * 8;
      bf16x8 ax = *(bf16x8*)&Ax[ab];
      bf16x8 at = *(bf16x8*)&At[ab];
#pragma unroll
      for (int nt = 0; nt < 2; ++nt) {
        f32x4 c = acc[mt][nt];
        c = __builtin_amdgcn_mfma_f32_16x16x32_bf16(ax, B0[ks][nt], c, 0, 0, 0);
        c = __builtin_amdgcn_mfma_f32_16x16x32_bf16(at, B1[ks][nt], c, 0, 0, 0);
        acc[mt][nt] = c;
      }
    }
  }

  // ---- epilogue ----
#pragma unroll
  for (int mt = 0; mt < 2; ++mt) {
    float pp[4], rr[4];
#pragma unroll
    for (int reg = 0; reg < 4; ++reg) {
      float h0 = fmaxf(acc[mt][0][reg] + b1f[0], 0.f);
      float h1 = fmaxf(acc[mt][1][reg] + b1f[1], 0.f);
      pp[reg] = h0 * w20f[0] + h1 * w20f[1];
      rr[reg] = h0 * w21f[0] + h1 * w21f[1];
    }
#pragma unroll
    for (int off = 1; off < 16; off <<= 1) {
#pragma unroll
      for (int reg = 0; reg < 4; ++reg) {
        pp[reg] += __shfl_xor(pp[reg], off);
        rr[reg] += __shfl_xor(rr[reg], off);
      }
    }
    if (col == 0) {
#pragma unroll
      for (int reg = 0; reg < 4; ++reg) {
        atomicAdd(&p_sh[mt * 16 + quad * 4 + reg], pp[reg]);
        atomicAdd(&r_sh[mt * 16 + quad * 4 + reg], rr[reg]);
      }
    }
  }
  __syncthreads();
  if (tid < CHUNK) {
    int gn = node0 + tid;
    if (gn < N) {
      p[gn] = p_sh[tid];
      r[gn] = dinv[gn] * r_sh[tid];
    }
  }
}

// ---------- layer-2 aggregation + sigmoid epilogue ----------
__global__ __launch_bounds__(256) void k_gather2_final(
    const int* __restrict__ pairs, const int* __restrict__ rp,
    const float* __restrict__ r2, const float* __restrict__ p,
    const float* __restrict__ dinv, const float* __restrict__ b2,
    float* __restrict__ out, int N) {
  int i = blockIdx.x * 256 + threadIdx.x;
  if (i >= N) return;
  int beg = rp[i], end = rp[i + 1];
  float a = 0.f;
  for (int j = beg; j < end; ++j) a += r2[pairs[j]];
  float z = p[i] - dinv[i] * a + b2[0];
  out[i] = 1.0f / (1.0f + expf(-z));
}

// ---------- launch ----------
extern "C" void kernel_launch(void* const* d_in, const int* in_sizes, int n_in,
                              void* d_out, int out_size, void* d_ws, size_t ws_size,
                              hipStream_t stream) {
  const float* x = (const float*)d_in[0];
  const int* ei = (const int*)d_in[1];
  const float* w10 = (const float*)d_in[2];
  const float* w11 = (const float*)d_in[3];
  const float* b1 = (const float*)d_in[4];
  const float* w20 = (const float*)d_in[5];
  const float* w21 = (const float*)d_in[6];
  const float* b2 = (const float*)d_in[7];
  float* out = (float*)d_out;
  int N = in_sizes[0] / F;
  int E = in_sizes[1] / 2;
  const int* src = ei;
  const int* dst = ei + E;
  int nbuckets = (N + 127) >> 7;

  // workspace layout (16B-aligned): ~44 MB total
  size_t off = 0;
  char* base = (char*)d_ws;
  auto take = [&](size_t bytes) {
    void* ptr = base + off;
    off += (bytes + 15) & ~(size_t)15;
    return ptr;
  };
  float* dinv = (float*)take((size_t)N * 4);
  float* p = (float*)take((size_t)N * 4);
  float* r = (float*)take((size_t)N * 4);
  int* rp = (int*)take(((size_t)N + 1) * 4);
  int* degA = (int*)take((size_t)N * 4);  // fallback only
  int* degB = (int*)take((size_t)N * 4);  // fallback only
  int* pos = (int*)take((size_t)N * 4);   // fallback only
  int* bsum = (int*)take(256 * 4);        // fallback only
  int* cntgD = (int*)take((size_t)nbuckets * NBLK * 4);
  int* cntgS = (int*)take((size_t)nbuckets * NBLK * 4);
  int* totD = (int*)take(((size_t)nbuckets + 1) * 4);
  int* totS = (int*)take(((size_t)nbuckets + 1) * 4);
  int* baseD = (int*)take(((size_t)nbuckets + 1) * 4);
  int* baseS = (int*)take(((size_t)nbuckets + 1) * 4);
  int* pairs = (int*)take((size_t)E * 4);
  unsigned* binnedD = (unsigned*)take((size_t)E * 4);
  unsigned char* binnedS = (unsigned char*)take((size_t)E);
  unsigned short* xb = (unsigned short*)take((size_t)N * F * 2);
  if (off > ws_size) return;

  int NF4 = N * (F / 4);
  int per = (E + NBLK - 1) / NBLK;

  if (nbuckets <= 1024) {
    k_prep2<<<NBLK, 1024, (size_t)nbuckets * 8, stream>>>(src, dst, x, xb, cntgD,
                                                          cntgS, E, NF4, nbuckets,
                                                          per);
    k_scanBk2<<<2 * nbuckets, NBLK, 0, stream>>>(cntgD, cntgS, totD, totS, nbuckets);
    k_scanTot<<<1, 1024, 0, stream>>>(totD, totS, baseD, baseS, nbuckets, E);
    k_binfill2<<<NBLK, 1024, (size_t)nbuckets * 16, stream>>>(
        src, dst, cntgD, cntgS, baseD, baseS, binnedD, binnedS, E, nbuckets, per);
    k_csr<<<nbuckets, 256, 0, stream>>>(binnedS, baseS, binnedD, baseD, dinv, rp,
                                        pairs, N, E);
  } else {
    int nb_scan = (N + SCAN_CHUNK - 1) / SCAN_CHUNK;
    hipMemsetAsync(degA, 0, 2 * (size_t)N * sizeof(int), stream);
    k_prep<<<2048, 256, 0, stream>>>(src, dst, x, degA, degB, xb, E, NF4);
    k_scanA<<<nb_scan, 256, 0, stream>>>(degB, rp, bsum, N);
    k_scanB<<<1, 256, 0, stream>>>(bsum, nb_scan);
    k_scanC<<<(N + 255) / 256, 256, 0, stream>>>(rp, bsum, pos, degA, dinv, N, E);
    k_fill<<<2048, 256, 0, stream>>>(src, dst, pos, pairs, E);
  }
  k_fused<<<(N + CHUNK - 1) / CHUNK, 256, 0, stream>>>(pairs, rp, xb, dinv, w10,
                                                       w11, b1, w20, w21, p, r, N);
  k_gather2_final<<<(N + 255) / 256, 256, 0, stream>>>(pairs, rp, r, p, dinv, b2,
                                                       out, N);
}

// Round 12
// 299.950 us; speedup vs baseline: 1.3069x; 1.3069x over previous
//
#include <hip/hip_runtime.h>
#include <math.h>

#define F 128
#define SCAN_CHUNK 1024
#define CHUNK 32   // nodes per chunk in mfma layer kernel
#define NBLK 128   // writer blocks in hist/binfill

typedef __attribute__((ext_vector_type(8))) short bf16x8;
typedef __attribute__((ext_vector_type(4))) float f32x4;

__device__ inline unsigned short f2bf(float v) {  // fp32 -> bf16 RNE
  unsigned u = __float_as_uint(v);
  unsigned r = (u + 0x7FFFu + ((u >> 16) & 1u)) >> 16;
  return (unsigned short)r;
}
__device__ inline float bf2f(unsigned short s) {
  return __uint_as_float(((unsigned)s) << 16);
}

// ---------- fused: dual bucket histogram + x -> bf16 conversion ----------
__global__ __launch_bounds__(1024) void k_prep2(const int* __restrict__ src,
                                                const int* __restrict__ dst,
                                                const float* __restrict__ x,
                                                unsigned short* __restrict__ xb,
                                                int* __restrict__ cntgD,
                                                int* __restrict__ cntgS, int E,
                                                int NF4, int nb, int per) {
  extern __shared__ int smem[];
  int* cd = smem;
  int* cs = smem + nb;
  int blk = blockIdx.x;
  int tid = threadIdx.x;
  for (int b = tid; b < nb; b += 1024) {
    cd[b] = 0;
    cs[b] = 0;
  }
  __syncthreads();
  int e0 = blk * per;
  int e1 = e0 + per;
  if (e1 > E) e1 = E;
  for (int e = e0 + tid; e < e1; e += 1024) {
    atomicAdd(&cd[dst[e] >> 7], 1);
    atomicAdd(&cs[src[e] >> 7], 1);
  }
  const float4* x4 = (const float4*)x;
  ushort4* xb4 = (ushort4*)xb;
  for (int i = blk * 1024 + tid; i < NF4; i += NBLK * 1024) {
    float4 v = x4[i];
    ushort4 o;
    o.x = f2bf(v.x);
    o.y = f2bf(v.y);
    o.z = f2bf(v.z);
    o.w = f2bf(v.w);
    xb4[i] = o;
  }
  __syncthreads();
  for (int b = tid; b < nb; b += 1024) {
    cntgD[b * NBLK + blk] = cd[b];
    cntgS[b * NBLK + blk] = cs[b];
  }
}

// per-bucket exclusive scan over NBLK writer blocks; emit bucket totals
__global__ __launch_bounds__(NBLK) void k_scanBk2(int* __restrict__ cntgD,
                                                  int* __restrict__ cntgS,
                                                  int* __restrict__ totD,
                                                  int* __restrict__ totS, int nb) {
  __shared__ int sh[NBLK];
  int b = blockIdx.x;
  int tid = threadIdx.x;
  int* cntg;
  int* tot;
  int bb;
  if (b < nb) {
    cntg = cntgD;
    tot = totD;
    bb = b;
  } else {
    cntg = cntgS;
    tot = totS;
    bb = b - nb;
  }
  int v = cntg[bb * NBLK + tid];
  int val = v;
  sh[tid] = val;
  __syncthreads();
  for (int off = 1; off < NBLK; off <<= 1) {
    int o = (tid >= off) ? sh[tid - off] : 0;
    __syncthreads();
    val += o;
    sh[tid] = val;
    __syncthreads();
  }
  cntg[bb * NBLK + tid] = val - v;  // exclusive within bucket
  if (tid == NBLK - 1) tot[bb] = val;
}

// exclusive scan of bucket totals -> bases (nb <= 1024); sentinel = E
__global__ __launch_bounds__(1024) void k_scanTot(const int* __restrict__ totD,
                                                  const int* __restrict__ totS,
                                                  int* __restrict__ baseD,
                                                  int* __restrict__ baseS, int nb,
                                                  int E) {
  __shared__ int sh[1024];
  int tid = threadIdx.x;
  int v = (tid < nb) ? totD[tid] : 0;
  int val = v;
  sh[tid] = val;
  __syncthreads();
  for (int off = 1; off < 1024; off <<= 1) {
    int o = (tid >= off) ? sh[tid - off] : 0;
    __syncthreads();
    val += o;
    sh[tid] = val;
    __syncthreads();
  }
  if (tid < nb) baseD[tid] = val - v;
  if (tid == 0) baseD[nb] = E;
  __syncthreads();
  v = (tid < nb) ? totS[tid] : 0;
  val = v;
  sh[tid] = val;
  __syncthreads();
  for (int off = 1; off < 1024; off <<= 1) {
    int o = (tid >= off) ? sh[tid - off] : 0;
    __syncthreads();
    val += o;
    sh[tid] = val;
    __syncthreads();
  }
  if (tid < nb) baseS[tid] = val - v;
  if (tid == 0) baseS[nb] = E;
}

// scatter edges into bucket-grouped arrays (no global atomics)
__global__ __launch_bounds__(1024) void k_binfill2(
    const int* __restrict__ src, const int* __restrict__ dst,
    const int* __restrict__ cntgD, const int* __restrict__ cntgS,
    const int* __restrict__ baseD, const int* __restrict__ baseS,
    unsigned* __restrict__ binnedD, unsigned char* __restrict__ binnedS, int E,
    int nb, int per) {
  extern __shared__ int smem[];
  int* bD = smem;
  int* cD = smem + nb;
  int* bS = smem + 2 * nb;
  int* cS = smem + 3 * nb;
  int blk = blockIdx.x;
  for (int b = threadIdx.x; b < nb; b += 1024) {
    bD[b] = baseD[b] + cntgD[b * NBLK + blk];
    cD[b] = 0;
    bS[b] = baseS[b] + cntgS[b * NBLK + blk];
    cS[b] = 0;
  }
  __syncthreads();
  int e0 = blk * per;
  int e1 = e0 + per;
  if (e1 > E) e1 = E;
  for (int e = e0 + threadIdx.x; e < e1; e += 1024) {
    int s = src[e];
    int d = dst[e];
    int bk = d >> 7;
    int rk = atomicAdd(&cD[bk], 1);
    binnedD[bD[bk] + rk] = ((unsigned)s << 7) | (unsigned)(d & 127);
    int bs = s >> 7;
    int rs = atomicAdd(&cS[bs], 1);
    binnedS[bS[bs] + rs] = (unsigned char)(s & 127);
  }
}

// fused per-bucket: dinv (from src byte stream) + rp/pairs (from dst stream)
__global__ __launch_bounds__(256) void k_csr(const unsigned char* __restrict__ binnedS,
                                             const int* __restrict__ baseS,
                                             const unsigned* __restrict__ binnedD,
                                             const int* __restrict__ baseD,
                                             float* __restrict__ dinv,
                                             int* __restrict__ rp,
                                             int* __restrict__ pairs, int N, int E) {
  __shared__ int cnt[128];
  __shared__ int sc[256];
  __shared__ int cur[128];
  int b = blockIdx.x;
  int tid = threadIdx.x;
  int node0 = b << 7;
  if (tid < 128) cnt[tid] = 0;
  __syncthreads();
  int sbeg = baseS[b], send = baseS[b + 1];
  for (int j = sbeg + tid; j < send; j += 256) atomicAdd(&cnt[binnedS[j]], 1);
  __syncthreads();
  if (tid < 128) {
    int node = node0 + tid;
    if (node < N) {
      int c = cnt[tid];
      dinv[node] = c > 0 ? rsqrtf((float)c) : 0.0f;
    }
    cnt[tid] = 0;
  }
  __syncthreads();
  int wbeg = baseD[b], wend = baseD[b + 1];
  for (int j = wbeg + tid; j < wend; j += 256) atomicAdd(&cnt[binnedD[j] & 127u], 1);
  __syncthreads();
  int v = (tid < 128) ? cnt[tid] : 0;
  int val = v;
  sc[tid] = val;
  __syncthreads();
  for (int off = 1; off < 128; off <<= 1) {
    int o = (tid >= off) ? sc[tid - off] : 0;
    __syncthreads();
    val += o;
    sc[tid] = val;
    __syncthreads();
  }
  if (tid < 128) {
    int excl = wbeg + val - v;
    int node = node0 + tid;
    if (node < N) rp[node] = excl;
    cur[tid] = excl;
  }
  if (b == 0 && tid == 0) rp[N] = E;
  __syncthreads();
  for (int j = wbeg + tid; j < wend; j += 256) {
    unsigned e = binnedD[j];
    int idx = atomicAdd(&cur[e & 127u], 1);
    pairs[idx] = (int)(e >> 7);
  }
}

// ---------- fallback path (atomic degrees + scan), for huge N ----------
__global__ __launch_bounds__(256) void k_prep(const int* __restrict__ src,
                                              const int* __restrict__ dst,
                                              const float* __restrict__ x,
                                              int* __restrict__ degA,
                                              int* __restrict__ degB,
                                              unsigned short* __restrict__ xb,
                                              int E, int NF4) {
  int t0 = blockIdx.x * 256 + threadIdx.x;
  int stride = gridDim.x * 256;
  for (int i = t0; i < E; i += stride) {
    atomicAdd(&degA[src[i]], 1);
    atomicAdd(&degB[dst[i]], 1);
  }
  const float4* x4 = (const float4*)x;
  ushort4* xb4 = (ushort4*)xb;
  for (int i = t0; i < NF4; i += stride) {
    float4 v = x4[i];
    ushort4 o;
    o.x = f2bf(v.x);
    o.y = f2bf(v.y);
    o.z = f2bf(v.z);
    o.w = f2bf(v.w);
    xb4[i] = o;
  }
}

__global__ __launch_bounds__(256) void k_scanA(const int* __restrict__ deg,
                                               int* __restrict__ rp,
                                               int* __restrict__ bsum, int N) {
  __shared__ int sh[256];
  int tid = threadIdx.x;
  int base = blockIdx.x * SCAN_CHUNK + tid * 4;
  int v0 = 0, v1 = 0, v2 = 0, v3 = 0;
  if (base + 0 < N) v0 = deg[base + 0];
  if (base + 1 < N) v1 = deg[base + 1];
  if (base + 2 < N) v2 = deg[base + 2];
  if (base + 3 < N) v3 = deg[base + 3];
  int ts = v0 + v1 + v2 + v3;
  int val = ts;
  sh[tid] = val;
  __syncthreads();
  for (int off = 1; off < 256; off <<= 1) {
    int other = (tid >= off) ? sh[tid - off] : 0;
    __syncthreads();
    val += other;
    sh[tid] = val;
    __syncthreads();
  }
  int excl = val - ts;
  if (base + 0 < N) rp[base + 0] = excl;
  if (base + 1 < N) rp[base + 1] = excl + v0;
  if (base + 2 < N) rp[base + 2] = excl + v0 + v1;
  if (base + 3 < N) rp[base + 3] = excl + v0 + v1 + v2;
  if (tid == 255) bsum[blockIdx.x] = val;
}

__global__ __launch_bounds__(256) void k_scanB(int* __restrict__ bsum, int nb) {
  __shared__ int sh[256];
  int tid = threadIdx.x;
  int ts = (tid < nb) ? bsum[tid] : 0;
  int val = ts;
  sh[tid] = val;
  __syncthreads();
  for (int off = 1; off < 256; off <<= 1) {
    int other = (tid >= off) ? sh[tid - off] : 0;
    __syncthreads();
    val += other;
    sh[tid] = val;
    __syncthreads();
  }
  if (tid < nb) bsum[tid] = val - ts;
}

__global__ __launch_bounds__(256) void k_scanC(int* __restrict__ rp,
                                               const int* __restrict__ bsum,
                                               int* __restrict__ pos,
                                               const int* __restrict__ degA,
                                               float* __restrict__ dinv, int N,
                                               int E) {
  int i = blockIdx.x * 256 + threadIdx.x;
  if (i < N) {
    int v = rp[i] + bsum[i >> 10];
    rp[i] = v;
    pos[i] = v;
    int d = degA[i];
    dinv[i] = d > 0 ? rsqrtf((float)d) : 0.0f;
  }
  if (i == 0) rp[N] = E;
}

__global__ __launch_bounds__(256) void k_fill(const int* __restrict__ src,
                                              const int* __restrict__ dst,
                                              int* __restrict__ pos,
                                              int* __restrict__ pairs, int E) {
  for (int e = blockIdx.x * 256 + threadIdx.x; e < E; e += gridDim.x * 256) {
    int s = src[e];
    int d = dst[e];
    int idx = atomicAdd(&pos[d], 1);
    pairs[idx] = s;
  }
}

// ---------- aggregation: one half-wave per node, 4-edge unroll ----------
// tb[i] = bf16( -dinv[i] * sum_{e: dst=i} dinv[src] * xb[src] )
__global__ __launch_bounds__(256) void k_gather1c(
    const int* __restrict__ pairs, const int* __restrict__ rp,
    const unsigned short* __restrict__ xb, const float* __restrict__ dinv,
    unsigned short* __restrict__ tb, int N) {
  int node = (blockIdx.x * 256 + threadIdx.x) >> 5;
  if (node >= N) return;
  int li = threadIdx.x & 31;
  int beg = rp[node], end = rp[node + 1];
  const uint2* x2 = (const uint2*)xb;
  float a0 = 0.f, a1 = 0.f, a2 = 0.f, a3 = 0.f;
  int j = beg;
  for (; j + 3 < end; j += 4) {  // 4 row-loads in flight
    int s0 = pairs[j], s1 = pairs[j + 1], s2 = pairs[j + 2], s3 = pairs[j + 3];
    float w0 = dinv[s0], w1 = dinv[s1], w2 = dinv[s2], w3 = dinv[s3];
    uint2 v0 = x2[(size_t)s0 * 32 + li];
    uint2 v1 = x2[(size_t)s1 * 32 + li];
    uint2 v2 = x2[(size_t)s2 * 32 + li];
    uint2 v3 = x2[(size_t)s3 * 32 + li];
    a0 += w0 * bf2f((unsigned short)v0.x) + w1 * bf2f((unsigned short)v1.x) +
          w2 * bf2f((unsigned short)v2.x) + w3 * bf2f((unsigned short)v3.x);
    a1 += w0 * bf2f((unsigned short)(v0.x >> 16)) +
          w1 * bf2f((unsigned short)(v1.x >> 16)) +
          w2 * bf2f((unsigned short)(v2.x >> 16)) +
          w3 * bf2f((unsigned short)(v3.x >> 16));
    a2 += w0 * bf2f((unsigned short)v0.y) + w1 * bf2f((unsigned short)v1.y) +
          w2 * bf2f((unsigned short)v2.y) + w3 * bf2f((unsigned short)v3.y);
    a3 += w0 * bf2f((unsigned short)(v0.y >> 16)) +
          w1 * bf2f((unsigned short)(v1.y >> 16)) +
          w2 * bf2f((unsigned short)(v2.y >> 16)) +
          w3 * bf2f((unsigned short)(v3.y >> 16));
  }
  for (; j < end; ++j) {
    int s0 = pairs[j];
    float w0 = dinv[s0];
    uint2 v0 = x2[(size_t)s0 * 32 + li];
    a0 += w0 * bf2f((unsigned short)v0.x);
    a1 += w0 * bf2f((unsigned short)(v0.x >> 16));
    a2 += w0 * bf2f((unsigned short)v0.y);
    a3 += w0 * bf2f((unsigned short)(v0.y >> 16));
  }
  float nd = -dinv[node];
  uint2 o;
  o.x = ((unsigned)f2bf(nd * a1) << 16) | f2bf(nd * a0);
  o.y = ((unsigned)f2bf(nd * a3) << 16) | f2bf(nd * a2);
  ((uint2*)tb)[(size_t)node * 32 + li] = o;
}

// ---------- MFMA fused layer v3 (bf16 x and t inputs, 2-term) ----------
// H = relu(Xb@W10 + T@W11 + b1); p = H.w20; r = dinv*(H.w21)
// Weights bf16-rounded (hi only): inputs are bf16-exact so the lo term only
// compensated weight rounding (~1e-3 in h) — 25x under error budget.
__global__ __launch_bounds__(256) void k_layer_mfma(
    const unsigned short* __restrict__ xb, const unsigned short* __restrict__ tb,
    const float* __restrict__ dinv, const float* __restrict__ w10,
    const float* __restrict__ w11, const float* __restrict__ b1,
    const float* __restrict__ w20, const float* __restrict__ w21,
    float* __restrict__ p, float* __restrict__ r, int N) {
  __shared__ __align__(16) short Ax[8 * 16 * 40];
  __shared__ __align__(16) short At[8 * 16 * 40];
  __shared__ float p_sh[CHUNK], r_sh[CHUNK];

  const int tid = threadIdx.x;
  const int wave = tid >> 6;
  const int lane = tid & 63;
  const int quad = lane >> 4;
  const int col = lane & 15;

  bf16x8 B0[4][2], B1[4][2];
  float b1f[2], w20f[2], w21f[2];
#pragma unroll
  for (int nt = 0; nt < 2; ++nt) {
    int f = wave * 32 + nt * 16 + col;
    b1f[nt] = b1[f];
    w20f[nt] = w20[f];
    w21f[nt] = w21[f];
  }
#pragma unroll
  for (int ks = 0; ks < 4; ++ks) {
#pragma unroll
    for (int nt = 0; nt < 2; ++nt) {
      int f = wave * 32 + nt * 16 + col;
      bf16x8 h0, h1;
#pragma unroll
      for (int j = 0; j < 8; ++j) {
        h0[j] = (short)f2bf(w10[(ks * 32 + quad * 8 + j) * F + f]);
        h1[j] = (short)f2bf(w11[(ks * 32 + quad * 8 + j) * F + f]);
      }
      B0[ks][nt] = h0;
      B1[ks][nt] = h1;
    }
  }

  const int nchunks = (N + CHUNK - 1) / CHUNK;
  for (int chunk = blockIdx.x; chunk < nchunks; chunk += gridDim.x) {
    int node0 = chunk * CHUNK;
    __syncthreads();

    {
      int nloc = tid >> 3;
      int k0 = (tid & 7) * 16;
      int gn = node0 + nloc;
      int mt = nloc >> 4, m = nloc & 15, ks = k0 >> 5, koff = k0 & 31;
      int base = ((mt * 4 + ks) * 16 + m) * 40 + koff;
      const uint2* xr = (const uint2*)(xb + (size_t)gn * F + k0);
      const uint2* tr = (const uint2*)(tb + (size_t)gn * F + k0);
      bool ok = (gn < N);
#pragma unroll
      for (int q4 = 0; q4 < 4; ++q4) {
        uint2 xv = ok ? xr[q4] : make_uint2(0u, 0u);
        uint2 tv = ok ? tr[q4] : make_uint2(0u, 0u);
        *(uint2*)&Ax[base + q4 * 4] = xv;
        *(uint2*)&At[base + q4 * 4] = tv;
      }
      if (tid < CHUNK) {
        p_sh[tid] = 0.f;
        r_sh[tid] = 0.f;
      }
    }
    __syncthreads();

    f32x4 acc[2][2];
#pragma unroll
    for (int mt = 0; mt < 2; ++mt)
#pragma unroll
      for (int nt = 0; nt < 2; ++nt) acc[mt][nt] = (f32x4)0.f;

#pragma unroll
    for (int mt = 0; mt < 2; ++mt) {
#pragma unroll
      for (int ks = 0; ks < 4; ++ks) {
        int ab = ((mt * 4 + ks) * 16 + col) * 40 + quad * 8;
        bf16x8 ax = *(bf16x8*)&Ax[ab];
        bf16x8 at = *(bf16x8*)&At[ab];
#pragma unroll
        for (int nt = 0; nt < 2; ++nt) {
          f32x4 c = acc[mt][nt];
          c = __builtin_amdgcn_mfma_f32_16x16x32_bf16(ax, B0[ks][nt], c, 0, 0, 0);
          c = __builtin_amdgcn_mfma_f32_16x16x32_bf16(at, B1[ks][nt], c, 0, 0, 0);
          acc[mt][nt] = c;
        }
      }
    }

#pragma unroll
    for (int mt = 0; mt < 2; ++mt) {
      float pp[4], rr[4];
#pragma unroll
      for (int reg = 0; reg < 4; ++reg) {
        float h0 = fmaxf(acc[mt][0][reg] + b1f[0], 0.f);
        float h1 = fmaxf(acc[mt][1][reg] + b1f[1], 0.f);
        pp[reg] = h0 * w20f[0] + h1 * w20f[1];
        rr[reg] = h0 * w21f[0] + h1 * w21f[1];
      }
#pragma unroll
      for (int off = 1; off < 16; off <<= 1) {
#pragma unroll
        for (int reg = 0; reg < 4; ++reg) {
          pp[reg] += __shfl_xor(pp[reg], off);
          rr[reg] += __shfl_xor(rr[reg], off);
        }
      }
      if (col == 0) {
#pragma unroll
        for (int reg = 0; reg < 4; ++reg) {
          atomicAdd(&p_sh[mt * 16 + quad * 4 + reg], pp[reg]);
          atomicAdd(&r_sh[mt * 16 + quad * 4 + reg], rr[reg]);
        }
      }
    }
    __syncthreads();
    if (tid < CHUNK) {
      int gn = node0 + tid;
      if (gn < N) {
        p[gn] = p_sh[tid];
        r[gn] = dinv[gn] * r_sh[tid];
      }
    }
  }
}

// ---------- layer-2 aggregation + sigmoid epilogue ----------
__global__ __launch_bounds__(256) void k_gather2_final(
    const int* __restrict__ pairs, const int* __restrict__ rp,
    const float* __restrict__ r2, const float* __restrict__ p,
    const float* __restrict__ dinv, const float* __restrict__ b2,
    float* __restrict__ out, int N) {
  int i = blockIdx.x * 256 + threadIdx.x;
  if (i >= N) return;
  int beg = rp[i], end = rp[i + 1];
  float a = 0.f;
  for (int j = beg; j < end; ++j) a += r2[pairs[j]];
  float z = p[i] - dinv[i] * a + b2[0];
  out[i] = 1.0f / (1.0f + expf(-z));
}

// ---------- launch ----------
extern "C" void kernel_launch(void* const* d_in, const int* in_sizes, int n_in,
                              void* d_out, int out_size, void* d_ws, size_t ws_size,
                              hipStream_t stream) {
  const float* x = (const float*)d_in[0];
  const int* ei = (const int*)d_in[1];
  const float* w10 = (const float*)d_in[2];
  const float* w11 = (const float*)d_in[3];
  const float* b1 = (const float*)d_in[4];
  const float* w20 = (const float*)d_in[5];
  const float* w21 = (const float*)d_in[6];
  const float* b2 = (const float*)d_in[7];
  float* out = (float*)d_out;
  int N = in_sizes[0] / F;
  int E = in_sizes[1] / 2;
  const int* src = ei;
  const int* dst = ei + E;
  int nbuckets = (N + 127) >> 7;

  // workspace layout (16B-aligned): ~62 MB total
  size_t off = 0;
  char* base = (char*)d_ws;
  auto take = [&](size_t bytes) {
    void* ptr = base + off;
    off += (bytes + 15) & ~(size_t)15;
    return ptr;
  };
  float* dinv = (float*)take((size_t)N * 4);
  float* p = (float*)take((size_t)N * 4);
  float* r = (float*)take((size_t)N * 4);
  int* rp = (int*)take(((size_t)N + 1) * 4);
  int* degA = (int*)take((size_t)N * 4);  // fallback only
  int* degB = (int*)take((size_t)N * 4);  // fallback only
  int* pos = (int*)take((size_t)N * 4);   // fallback only
  int* bsum = (int*)take(256 * 4);        // fallback only
  int* cntgD = (int*)take((size_t)nbuckets * NBLK * 4);
  int* cntgS = (int*)take((size_t)nbuckets * NBLK * 4);
  int* totD = (int*)take(((size_t)nbuckets + 1) * 4);
  int* totS = (int*)take(((size_t)nbuckets + 1) * 4);
  int* baseD = (int*)take(((size_t)nbuckets + 1) * 4);
  int* baseS = (int*)take(((size_t)nbuckets + 1) * 4);
  int* pairs = (int*)take((size_t)E * 4);
  unsigned short* xb = (unsigned short*)take((size_t)N * F * 2);
  unsigned short* tb = (unsigned short*)take((size_t)N * F * 2);
  if (off > ws_size) return;
  // binnedD (4B/edge) and binnedS (1B/edge) alias tb: dead before tb is written
  unsigned* binnedD = (unsigned*)tb;
  unsigned char* binnedS = (unsigned char*)tb + (((size_t)E * 4 + 255) & ~(size_t)255);

  int NF4 = N * (F / 4);
  int per = (E + NBLK - 1) / NBLK;

  if (nbuckets <= 1024 && (size_t)E * 5 + 256 <= (size_t)N * F * 2) {
    k_prep2<<<NBLK, 1024, (size_t)nbuckets * 8, stream>>>(src, dst, x, xb, cntgD,
                                                          cntgS, E, NF4, nbuckets,
                                                          per);
    k_scanBk2<<<2 * nbuckets, NBLK, 0, stream>>>(cntgD, cntgS, totD, totS, nbuckets);
    k_scanTot<<<1, 1024, 0, stream>>>(totD, totS, baseD, baseS, nbuckets, E);
    k_binfill2<<<NBLK, 1024, (size_t)nbuckets * 16, stream>>>(
        src, dst, cntgD, cntgS, baseD, baseS, binnedD, binnedS, E, nbuckets, per);
    k_csr<<<nbuckets, 256, 0, stream>>>(binnedS, baseS, binnedD, baseD, dinv, rp,
                                        pairs, N, E);
  } else {
    int nb_scan = (N + SCAN_CHUNK - 1) / SCAN_CHUNK;
    hipMemsetAsync(degA, 0, 2 * (size_t)N * sizeof(int), stream);
    k_prep<<<2048, 256, 0, stream>>>(src, dst, x, degA, degB, xb, E, NF4);
    k_scanA<<<nb_scan, 256, 0, stream>>>(degB, rp, bsum, N);
    k_scanB<<<1, 256, 0, stream>>>(bsum, nb_scan);
    k_scanC<<<(N + 255) / 256, 256, 0, stream>>>(rp, bsum, pos, degA, dinv, N, E);
    k_fill<<<2048, 256, 0, stream>>>(src, dst, pos, pairs, E);
  }
  k_gather1c<<<(N + 7) / 8, 256, 0, stream>>>(pairs, rp, xb, dinv, tb, N);
  k_layer_mfma<<<512, 256, 0, stream>>>(xb, tb, dinv, w10, w11, b1, w20, w21, p, r,
                                        N);
  k_gather2_final<<<(N + 255) / 256, 256, 0, stream>>>(pairs, rp, r, p, dinv, b2,
                                                       out, N);
}